// Round 2
// baseline (452.816 us; speedup 1.0000x reference)
//
#include <hip/hip_runtime.h>

// Dice coefficient: argmax over C=4 classes per pixel + histogram counts.
// Shapes fixed by the problem: B=32, C=4, H=W=512.
constexpr int kHW = 512 * 512;   // 262144 pixels per plane (65536 float4-groups)
constexpr int kC  = 4;

// ws layout (12 x unsigned): [0..3]=pred_cnt, [4..7]=true_cnt, [8..11]=tp

__device__ __forceinline__ void do_pixel(float c0, float c1, float c2, float c3, int tr,
                                         unsigned long long& predp,
                                         unsigned long long& truep,
                                         unsigned long long& tpp) {
    // First-max-wins argmax (strict >) matches jnp.argmax semantics.
    int   pred = 0;
    float best = c0;
    if (c1 > best) { best = c1; pred = 1; }
    if (c2 > best) { best = c2; pred = 2; }
    if (c3 > best) { best = c3; pred = 3; }
    predp += 1ull << (pred << 4);
    truep += 1ull << (tr << 4);
    if (pred == tr) tpp += 1ull << (pred << 4);
}

// 2048 blocks x 256 threads x 4 groups/thread = 2,097,152 groups (exact cover).
// Each block covers 1024 consecutive groups; 1024 | 65536, so the whole block
// sits in one batch plane -> b is block-uniform.
__global__ __launch_bounds__(256)
void dice_count_kernel(const int* __restrict__ tm, const float* __restrict__ outp,
                       unsigned* __restrict__ cnt) {
    const int b     = blockIdx.x >> 6;                       // 64 blocks per batch
    const int gbase = ((blockIdx.x & 63) << 10) + threadIdx.x; // group idx in plane

    const float* pb = outp + (size_t)b * kC * kHW;
    const int*   tb = tm   + (size_t)b * kHW;

    // Issue ALL loads first — 20 float4 + 4 int4 in flight per thread.
    float4 v[4][4];
    int4   t[4];
    #pragma unroll
    for (int k = 0; k < 4; ++k) {
        const int rem = (gbase + (k << 8)) << 2;             // pixel offset in plane
        v[k][0] = *(const float4*)(pb + rem);
        v[k][1] = *(const float4*)(pb + kHW + rem);
        v[k][2] = *(const float4*)(pb + 2 * kHW + rem);
        v[k][3] = *(const float4*)(pb + 3 * kHW + rem);
        t[k]    = *(const int4*)(tb + rem);
    }

    // Packed per-thread counters: four 16-bit fields (one per class) in a u64.
    // Max 16 pixels/thread -> fields stay tiny; after block reduce <= 1024.
    unsigned long long predp = 0, truep = 0, tpp = 0;
    #pragma unroll
    for (int k = 0; k < 4; ++k) {
        do_pixel(v[k][0].x, v[k][1].x, v[k][2].x, v[k][3].x, t[k].x, predp, truep, tpp);
        do_pixel(v[k][0].y, v[k][1].y, v[k][2].y, v[k][3].y, t[k].y, predp, truep, tpp);
        do_pixel(v[k][0].z, v[k][1].z, v[k][2].z, v[k][3].z, t[k].z, predp, truep, tpp);
        do_pixel(v[k][0].w, v[k][1].w, v[k][2].w, v[k][3].w, t[k].w, predp, truep, tpp);
    }

    // Wave-64 butterfly reduction.
    for (int off = 32; off > 0; off >>= 1) {
        predp += __shfl_down(predp, off);
        truep += __shfl_down(truep, off);
        tpp   += __shfl_down(tpp, off);
    }

    __shared__ unsigned long long s[3][4];
    const int lane = threadIdx.x & 63;
    const int wave = threadIdx.x >> 6;
    if (lane == 0) { s[0][wave] = predp; s[1][wave] = truep; s[2][wave] = tpp; }
    __syncthreads();

    if (threadIdx.x == 0) {
        unsigned long long P = s[0][0] + s[0][1] + s[0][2] + s[0][3];
        unsigned long long T = s[1][0] + s[1][1] + s[1][2] + s[1][3];
        unsigned long long Q = s[2][0] + s[2][1] + s[2][2] + s[2][3];
        #pragma unroll
        for (int c = 0; c < 4; ++c) {
            atomicAdd(&cnt[c],     (unsigned)((P >> (c * 16)) & 0xFFFF));
            atomicAdd(&cnt[4 + c], (unsigned)((T >> (c * 16)) & 0xFFFF));
            atomicAdd(&cnt[8 + c], (unsigned)((Q >> (c * 16)) & 0xFFFF));
        }
    }
}

__global__ void dice_final_kernel(const unsigned* __restrict__ cnt,
                                  float* __restrict__ out) {
    const int c = (int)threadIdx.x + 1;   // classes 1..3 (skip background)
    if (c <= 3) {
        const float tp  = (float)cnt[8 + c];
        const float den = (float)cnt[c] + (float)cnt[4 + c];
        out[c - 1] = 2.0f * tp / den;
    }
}

extern "C" void kernel_launch(void* const* d_in, const int* in_sizes, int n_in,
                              void* d_out, int out_size, void* d_ws, size_t ws_size,
                              hipStream_t stream) {
    const int*   tm = (const int*)d_in[0];    // true_masks [B,H,W] int32
    const float* op = (const float*)d_in[1];  // out        [B,C,H,W] f32
    unsigned*   cnt = (unsigned*)d_ws;

    // ws is re-poisoned to 0xAA before every timed call: zero the counters.
    hipMemsetAsync(cnt, 0, 12 * sizeof(unsigned), stream);

    dice_count_kernel<<<2048, 256, 0, stream>>>(tm, op, cnt);
    dice_final_kernel<<<1, 64, 0, stream>>>(cnt, (float*)d_out);
}

// Round 3
// 212.514 us; speedup vs baseline: 2.1308x; 2.1308x over previous
//
#include <hip/hip_runtime.h>

// Dice coefficient: argmax over C=4 classes per pixel + histogram counts.
// Shapes fixed by the problem: B=32, C=4, H=W=512.
constexpr int kHW       = 512 * 512;  // 262144 pixels per plane
constexpr int kC        = 4;
constexpr int kReplicas = 16;         // atomic-contention spreading
constexpr int kLine     = 32;         // 32 uints = 128 B = one cache line

// ws layout: (replica r, counter i) at ws[(r*12 + i) * kLine]  -> its own line.
// counters: [0..3]=pred_cnt, [4..7]=true_cnt, [8..11]=tp
constexpr int kWsInts = kReplicas * 12 * kLine;  // 6144 uints = 24 KB

__global__ __launch_bounds__(256)
void dice_count_kernel(const int* __restrict__ tm, const float* __restrict__ outp,
                       unsigned* __restrict__ cnt, int num_groups) {
    // Packed per-thread counters: four 16-bit fields (one per class) in a u64.
    // 8 groups = 32 pixels per thread; block totals <= 8192 per field.
    unsigned long long predp = 0, truep = 0, tpp = 0;

    const int stride = gridDim.x * blockDim.x;   // 262144: each iter jumps 4 planes
    for (int g = blockIdx.x * blockDim.x + threadIdx.x; g < num_groups; g += stride) {
        const int b   = g >> 16;             // 65536 float4-groups per batch plane
        const int rem = (g & 0xFFFF) << 2;   // pixel offset within the plane
        const float* base = outp + ((size_t)b * kC) * kHW + rem;
        const float4 v0 = *(const float4*)(base);
        const float4 v1 = *(const float4*)(base + kHW);
        const float4 v2 = *(const float4*)(base + 2 * kHW);
        const float4 v3 = *(const float4*)(base + 3 * kHW);
        const int4   t  = *(const int4*)(tm + (size_t)g * 4);

        // First-max-wins argmax (strict >) matches jnp.argmax semantics.
        #define DO_PIXEL(f, tf)                                        \
        {                                                              \
            int   pred = 0;                                            \
            float best = v0.f;                                         \
            if (v1.f > best) { best = v1.f; pred = 1; }                \
            if (v2.f > best) { best = v2.f; pred = 2; }                \
            if (v3.f > best) { best = v3.f; pred = 3; }                \
            predp += 1ull << (pred << 4);                              \
            truep += 1ull << (t.tf << 4);                              \
            if (pred == t.tf) tpp += 1ull << (pred << 4);              \
        }
        DO_PIXEL(x, x) DO_PIXEL(y, y) DO_PIXEL(z, z) DO_PIXEL(w, w)
        #undef DO_PIXEL
    }

    // Wave-64 butterfly reduction (fields <= 2048/wave, fits 16 bits).
    for (int off = 32; off > 0; off >>= 1) {
        predp += __shfl_down(predp, off);
        truep += __shfl_down(truep, off);
        tpp   += __shfl_down(tpp, off);
    }

    __shared__ unsigned long long s[3][4];
    const int lane = threadIdx.x & 63;
    const int wave = threadIdx.x >> 6;
    if (lane == 0) { s[0][wave] = predp; s[1][wave] = truep; s[2][wave] = tpp; }
    __syncthreads();

    if (threadIdx.x == 0) {
        unsigned long long P = s[0][0] + s[0][1] + s[0][2] + s[0][3];  // <= 8192/field
        unsigned long long T = s[1][0] + s[1][1] + s[1][2] + s[1][3];
        unsigned long long Q = s[2][0] + s[2][1] + s[2][2] + s[2][3];
        // Each (replica, counter) pair lives on its own 128 B line: atomics from
        // different blocks collide only 1-in-16, and the 12 counters never share
        // a line -> no single-TCC-bank serialization.
        unsigned* rep = cnt + (blockIdx.x & (kReplicas - 1)) * 12 * kLine;
        #pragma unroll
        for (int c = 0; c < 4; ++c) {
            atomicAdd(&rep[c * kLine],       (unsigned)((P >> (c * 16)) & 0xFFFF));
            atomicAdd(&rep[(4 + c) * kLine], (unsigned)((T >> (c * 16)) & 0xFFFF));
            atomicAdd(&rep[(8 + c) * kLine], (unsigned)((Q >> (c * 16)) & 0xFFFF));
        }
    }
}

__global__ void dice_final_kernel(const unsigned* __restrict__ cnt,
                                  float* __restrict__ out) {
    __shared__ float tot[12];
    if (threadIdx.x < 12) {
        unsigned sum = 0;
        #pragma unroll
        for (int r = 0; r < kReplicas; ++r)
            sum += cnt[(r * 12 + (int)threadIdx.x) * kLine];
        tot[threadIdx.x] = (float)sum;
    }
    __syncthreads();
    if (threadIdx.x >= 1 && threadIdx.x < 4) {   // classes 1..3 (skip background)
        const int c = (int)threadIdx.x;
        out[c - 1] = 2.0f * tot[8 + c] / (tot[c] + tot[4 + c]);
    }
}

extern "C" void kernel_launch(void* const* d_in, const int* in_sizes, int n_in,
                              void* d_out, int out_size, void* d_ws, size_t ws_size,
                              hipStream_t stream) {
    const int*   tm = (const int*)d_in[0];    // true_masks [B,H,W] int32
    const float* op = (const float*)d_in[1];  // out        [B,C,H,W] f32
    unsigned*   cnt = (unsigned*)d_ws;

    const int P = in_sizes[0];        // B*H*W = 8388608 pixels
    const int num_groups = P / 4;     // float4 groups

    // ws is re-poisoned to 0xAA before every timed call: zero the counters.
    hipMemsetAsync(cnt, 0, kWsInts * sizeof(unsigned), stream);

    dice_count_kernel<<<1024, 256, 0, stream>>>(tm, op, cnt, num_groups);
    dice_final_kernel<<<1, 64, 0, stream>>>(cnt, (float*)d_out);
}